// Round 1
// baseline (1745.912 us; speedup 1.0000x reference)
//
#include <hip/hip_runtime.h>
#include <math.h>

#define H128 128

// ---------- helpers ----------
__device__ __forceinline__ unsigned long long enc64(double d) {
    unsigned long long b = (unsigned long long)__double_as_longlong(d);
    return (b & 0x8000000000000000ULL) ? ~b : (b | 0x8000000000000000ULL);
}

// ---------- K1: logits[n] = dot(x[n], w_lead) + b_lead  (fp64) ----------
__global__ void k_logits(const float* __restrict__ x, const float* __restrict__ wl,
                         const float* __restrict__ bl, double* __restrict__ logits, int N) {
    int wave = (int)((blockIdx.x * (unsigned)blockDim.x + threadIdx.x) >> 6);
    int lane = threadIdx.x & 63;
    if (wave >= N) return;
    const float* xr = x + (size_t)wave * H128;
    double s = (double)xr[lane] * (double)wl[lane]
             + (double)xr[lane + 64] * (double)wl[lane + 64];
#pragma unroll
    for (int off = 32; off > 0; off >>= 1) s += __shfl_down(s, off);
    if (lane == 0) logits[wave] = s + (double)bl[0];
}

// ---------- K2: per-dst segment max of logits[src] over extended edges ----------
__global__ void k_segmax(const int* __restrict__ ei, const double* __restrict__ logits,
                         unsigned long long* __restrict__ segmax, int E, int N) {
    int t = blockIdx.x * blockDim.x + threadIdx.x;
    int M = E + N;
    if (t >= M) return;
    int src, dst;
    if (t < E) { src = ei[t]; dst = ei[E + t]; } else { src = dst = t - E; }
    atomicMax(&segmax[dst], enc64(logits[src]));
}

// ---------- K3: leader[dst] = max src achieving the max ----------
__global__ void k_leader(const int* __restrict__ ei, const double* __restrict__ logits,
                         const unsigned long long* __restrict__ segmax,
                         int* __restrict__ leader, int E, int N) {
    int t = blockIdx.x * blockDim.x + threadIdx.x;
    int M = E + N;
    if (t >= M) return;
    int src, dst;
    if (t < E) { src = ei[t]; dst = ei[E + t]; } else { src = dst = t - E; }
    if (enc64(logits[src]) == segmax[dst]) atomicMax(&leader[dst], src);
}

// ---------- K4: scatter-add x[row] into sums[col], count edges ----------
__global__ void k_scatter(const int* __restrict__ ei, const float* __restrict__ x,
                          float* __restrict__ sums, float* __restrict__ cnt, int E) {
    long long g = (long long)blockIdx.x * blockDim.x + threadIdx.x;
    if (g >= (long long)E * 32) return;
    int e = (int)(g >> 5);
    int q = (int)(g & 31);
    int r = ei[e], c = ei[E + e];
    const float4 v = *reinterpret_cast<const float4*>(x + (size_t)r * H128 + q * 4);
    float* d = sums + (size_t)c * H128 + q * 4;
    unsafeAtomicAdd(d + 0, v.x);
    unsafeAtomicAdd(d + 1, v.y);
    unsafeAtomicAdd(d + 2, v.z);
    unsafeAtomicAdd(d + 3, v.w);
    if (q == 0) unsafeAtomicAdd(cnt + c, 1.0f);
}

// ---------- K5/K6: out[i,:] = act( (A[i,:] * rowscale) @ W + bias ) ----------
// W is [128][128] k-major in global; staged whole in LDS (64 KB).
// Block: 256 threads, 64 rows x 128 cols tile; per-thread 8 rows x 4 cols.
__global__ __launch_bounds__(256, 2) void k_gemm128(
        const float* __restrict__ A, const float* __restrict__ W,
        const float* __restrict__ bias, const float* __restrict__ cnt,
        float* __restrict__ out, int N, int dogelu) {
    __shared__ float wl[128 * 128];
    {
        const float4* Wv = reinterpret_cast<const float4*>(W);
        float4* wv = reinterpret_cast<float4*>(wl);
        for (int i = threadIdx.x; i < 4096; i += 256) wv[i] = Wv[i];
    }
    __syncthreads();

    const int tx = threadIdx.x & 31;   // col group: cols c0..c0+3
    const int ty = threadIdx.x >> 5;   // 0..7 row phase
    const int c0 = tx * 4;
    const int r0 = blockIdx.x * 64;

    float acc[8][4];
#pragma unroll
    for (int rr = 0; rr < 8; ++rr)
#pragma unroll
        for (int j = 0; j < 4; ++j) acc[rr][j] = 0.0f;

    int rows[8];
#pragma unroll
    for (int rr = 0; rr < 8; ++rr) {
        int r = r0 + ty + 8 * rr;
        rows[rr] = (r < N) ? r : (N - 1);
    }

    for (int k4 = 0; k4 < 32; ++k4) {
        const int kb = k4 * 4;
        const float4 w0 = *reinterpret_cast<const float4*>(&wl[(kb + 0) * 128 + c0]);
        const float4 w1 = *reinterpret_cast<const float4*>(&wl[(kb + 1) * 128 + c0]);
        const float4 w2 = *reinterpret_cast<const float4*>(&wl[(kb + 2) * 128 + c0]);
        const float4 w3 = *reinterpret_cast<const float4*>(&wl[(kb + 3) * 128 + c0]);
#pragma unroll
        for (int rr = 0; rr < 8; ++rr) {
            const float4 a = *reinterpret_cast<const float4*>(A + (size_t)rows[rr] * H128 + kb);
            acc[rr][0] = fmaf(a.w, w3.x, fmaf(a.z, w2.x, fmaf(a.y, w1.x, fmaf(a.x, w0.x, acc[rr][0]))));
            acc[rr][1] = fmaf(a.w, w3.y, fmaf(a.z, w2.y, fmaf(a.y, w1.y, fmaf(a.x, w0.y, acc[rr][1]))));
            acc[rr][2] = fmaf(a.w, w3.z, fmaf(a.z, w2.z, fmaf(a.y, w1.z, fmaf(a.x, w0.z, acc[rr][2]))));
            acc[rr][3] = fmaf(a.w, w3.w, fmaf(a.z, w2.w, fmaf(a.y, w1.w, fmaf(a.x, w0.w, acc[rr][3]))));
        }
    }

    const float b0 = bias[c0 + 0], b1v = bias[c0 + 1], b2v = bias[c0 + 2], b3v = bias[c0 + 3];
#pragma unroll
    for (int rr = 0; rr < 8; ++rr) {
        int r = r0 + ty + 8 * rr;
        if (r >= N) continue;
        float s = 1.0f;
        if (cnt) s = 1.0f / fmaxf(cnt[r], 1.0f);
        float o[4];
        o[0] = acc[rr][0] * s + b0;
        o[1] = acc[rr][1] * s + b1v;
        o[2] = acc[rr][2] * s + b2v;
        o[3] = acc[rr][3] * s + b3v;
        if (dogelu) {
#pragma unroll
            for (int j = 0; j < 4; ++j)
                o[j] = 0.5f * o[j] * (1.0f + erff(o[j] * 0.70710678118654752440f));
        }
        float4 ov = make_float4(o[0], o[1], o[2], o[3]);
        *reinterpret_cast<float4*>(out + (size_t)r * H128 + c0) = ov;
    }
}

// ---------- K7: out[i] = reports[leader[i]] ----------
__global__ void k_gather(const int* __restrict__ leader, const float* __restrict__ reports,
                         float* __restrict__ out, int N) {
    long long g = (long long)blockIdx.x * blockDim.x + threadIdx.x;
    if (g >= (long long)N * 32) return;
    int i = (int)(g >> 5);
    int q = (int)(g & 31);
    int l = leader[i];
    if (l < 0) l = i;
    *reinterpret_cast<float4*>(out + (size_t)i * H128 + q * 4) =
        *reinterpret_cast<const float4*>(reports + (size_t)l * H128 + q * 4);
}

extern "C" void kernel_launch(void* const* d_in, const int* in_sizes, int n_in,
                              void* d_out, int out_size, void* d_ws, size_t ws_size,
                              hipStream_t stream) {
    const float* x     = (const float*)d_in[0];
    const int*   ei    = (const int*)d_in[1];
    const float* wlead = (const float*)d_in[2];
    const float* blead = (const float*)d_in[3];
    const float* w1    = (const float*)d_in[4];
    const float* b1    = (const float*)d_in[5];
    const float* w2    = (const float*)d_in[6];
    const float* b2    = (const float*)d_in[7];
    float* out = (float*)d_out;

    const int N = in_sizes[0] / H128;
    const int E = in_sizes[1] / 2;

    char* ws = (char*)d_ws;
    size_t off = 0;
    float* sums = (float*)(ws + off); off += (size_t)N * H128 * 4;   // 51.2 MB
    float* hbuf = (float*)(ws + off); off += (size_t)N * H128 * 4;   // 51.2 MB
    double* logits = (double*)(ws + off); off += (size_t)N * 8;
    unsigned long long* segmax = (unsigned long long*)(ws + off); off += (size_t)N * 8;
    int* leader = (int*)(ws + off); off += (size_t)N * 4;
    float* cnt = (float*)(ws + off); off += (size_t)N * 4;
    float* reports = sums;  // reuse: sums no longer needed once hbuf exists

    hipMemsetAsync(sums, 0, (size_t)N * H128 * 4, stream);
    hipMemsetAsync(segmax, 0, (size_t)N * 8, stream);
    hipMemsetAsync(leader, 0xFF, (size_t)N * 4, stream);
    hipMemsetAsync(cnt, 0, (size_t)N * 4, stream);

    k_logits<<<(N + 3) / 4, 256, 0, stream>>>(x, wlead, blead, logits, N);

    const int M = E + N;
    k_segmax<<<(M + 255) / 256, 256, 0, stream>>>(ei, logits, segmax, E, N);
    k_leader<<<(M + 255) / 256, 256, 0, stream>>>(ei, logits, segmax, leader, E, N);

    const long long sc = (long long)E * 32;
    k_scatter<<<(int)((sc + 255) / 256), 256, 0, stream>>>(ei, x, sums, cnt, E);

    k_gemm128<<<(N + 63) / 64, 256, 0, stream>>>(sums, w1, b1, cnt, hbuf, N, 1);
    k_gemm128<<<(N + 63) / 64, 256, 0, stream>>>(hbuf, w2, b2, nullptr, reports, N, 0);

    const long long gc = (long long)N * 32;
    k_gather<<<(int)((gc + 255) / 256), 256, 0, stream>>>(leader, reports, out, N);
}

// Round 2
// 525.991 us; speedup vs baseline: 3.3193x; 3.3193x over previous
//
#include <hip/hip_runtime.h>
#include <math.h>

#define H128 128
#define CHUNK 1024

// ---------- helpers ----------
__device__ __forceinline__ unsigned long long enc64(double d) {
    unsigned long long b = (unsigned long long)__double_as_longlong(d);
    return (b & 0x8000000000000000ULL) ? ~b : (b | 0x8000000000000000ULL);
}

// ---------- K1: logits[n] = dot(x[n], w_lead) + b_lead  (fp64) ----------
__global__ void k_logits(const float* __restrict__ x, const float* __restrict__ wl,
                         const float* __restrict__ bl, double* __restrict__ logits, int N) {
    int wave = (int)((blockIdx.x * (unsigned)blockDim.x + threadIdx.x) >> 6);
    int lane = threadIdx.x & 63;
    if (wave >= N) return;
    const float* xr = x + (size_t)wave * H128;
    double s = (double)xr[lane] * (double)wl[lane]
             + (double)xr[lane + 64] * (double)wl[lane + 64];
#pragma unroll
    for (int off = 32; off > 0; off >>= 1) s += __shfl_down(s, off);
    if (lane == 0) logits[wave] = s + (double)bl[0];
}

// ---------- K2: per-dst segment max of logits[src] over extended edges ----------
__global__ void k_segmax(const int* __restrict__ ei, const double* __restrict__ logits,
                         unsigned long long* __restrict__ segmax, int E, int N) {
    int t = blockIdx.x * blockDim.x + threadIdx.x;
    int M = E + N;
    if (t >= M) return;
    int src, dst;
    if (t < E) { src = ei[t]; dst = ei[E + t]; } else { src = dst = t - E; }
    atomicMax(&segmax[dst], enc64(logits[src]));
}

// ---------- K3: leader[dst] = max src achieving the max ----------
__global__ void k_leader(const int* __restrict__ ei, const double* __restrict__ logits,
                         const unsigned long long* __restrict__ segmax,
                         int* __restrict__ leader, int E, int N) {
    int t = blockIdx.x * blockDim.x + threadIdx.x;
    int M = E + N;
    if (t >= M) return;
    int src, dst;
    if (t < E) { src = ei[t]; dst = ei[E + t]; } else { src = dst = t - E; }
    if (enc64(logits[src]) == segmax[dst]) atomicMax(&leader[dst], src);
}

// ---------- CSR build: histogram ----------
__global__ void k_hist(const int* __restrict__ ei, int* __restrict__ deg, int E) {
    int t = blockIdx.x * blockDim.x + threadIdx.x;
    if (t >= E) return;
    atomicAdd(&deg[ei[E + t]], 1);
}

// ---------- CSR build: per-chunk partial sums ----------
__global__ void k_scan_partial(const int* __restrict__ deg, int* __restrict__ part, int N) {
    __shared__ int sm[256];
    int base = blockIdx.x * CHUNK;
    int s = 0;
    for (int i = threadIdx.x; i < CHUNK; i += 256) {
        int g = base + i;
        if (g < N) s += deg[g];
    }
    sm[threadIdx.x] = s;
    __syncthreads();
    for (int o = 128; o > 0; o >>= 1) {
        if (threadIdx.x < o) sm[threadIdx.x] += sm[threadIdx.x + o];
        __syncthreads();
    }
    if (threadIdx.x == 0) part[blockIdx.x] = sm[0];
}

// ---------- CSR build: scan the (few) chunk partials, single thread ----------
__global__ void k_scan_offsets(int* __restrict__ part, int nch, int* __restrict__ starts, int N) {
    int acc = 0;
    for (int i = 0; i < nch; ++i) { int v = part[i]; part[i] = acc; acc += v; }
    starts[N] = acc;   // = E
}

// ---------- CSR build: write exclusive scan per chunk ----------
__global__ void k_scan_write(const int* __restrict__ deg, const int* __restrict__ part,
                             int* __restrict__ starts, int* __restrict__ cursor, int N) {
    __shared__ int sm[256];
    int base = blockIdx.x * CHUNK;
    int t = threadIdx.x;
    int i0 = base + t * 4;
    int v[4], ts = 0;
#pragma unroll
    for (int j = 0; j < 4; ++j) {
        int g = i0 + j;
        v[j] = (g < N) ? deg[g] : 0;
        ts += v[j];
    }
    sm[t] = ts;
    __syncthreads();
    for (int o = 1; o < 256; o <<= 1) {
        int add = (t >= o) ? sm[t - o] : 0;
        __syncthreads();
        sm[t] += add;
        __syncthreads();
    }
    int excl = sm[t] - ts + part[blockIdx.x];
#pragma unroll
    for (int j = 0; j < 4; ++j) {
        int g = i0 + j;
        if (g < N) { starts[g] = excl; cursor[g] = excl; excl += v[j]; }
    }
}

// ---------- CSR build: fill edge slots ----------
__global__ void k_fill(const int* __restrict__ ei, int* __restrict__ cursor,
                       int* __restrict__ csr, int E) {
    int t = blockIdx.x * blockDim.x + threadIdx.x;
    if (t >= E) return;
    int r = ei[t], c = ei[E + t];
    int pos = atomicAdd(&cursor[c], 1);
    csr[pos] = r;
}

// ---------- K4': gather-aggregate mean. 32 lanes per dst, float4/lane ----------
__global__ __launch_bounds__(256) void k_aggregate(const int* __restrict__ starts,
                                                   const int* __restrict__ csr,
                                                   const float* __restrict__ x,
                                                   float* __restrict__ mean, int N) {
    int d = blockIdx.x * 8 + (threadIdx.x >> 5);
    int lane = threadIdx.x & 31;
    if (d >= N) return;
    int s = starts[d], e = starts[d + 1];
    float4 acc = make_float4(0.f, 0.f, 0.f, 0.f);
    for (int j = s; j < e; ++j) {
        int r = csr[j];
        const float4 v = *reinterpret_cast<const float4*>(x + (size_t)r * H128 + lane * 4);
        acc.x += v.x; acc.y += v.y; acc.z += v.z; acc.w += v.w;
    }
    float inv = 1.0f / fmaxf((float)(e - s), 1.0f);
    acc.x *= inv; acc.y *= inv; acc.z *= inv; acc.w *= inv;
    *reinterpret_cast<float4*>(mean + (size_t)d * H128 + lane * 4) = acc;
}

// ---------- K5/K6: out[i,:] = act( A[i,:] @ W + bias ) ----------
__global__ __launch_bounds__(256, 2) void k_gemm128(
        const float* __restrict__ A, const float* __restrict__ W,
        const float* __restrict__ bias, float* __restrict__ out, int N, int dogelu) {
    __shared__ float wl[128 * 128];
    {
        const float4* Wv = reinterpret_cast<const float4*>(W);
        float4* wv = reinterpret_cast<float4*>(wl);
        for (int i = threadIdx.x; i < 4096; i += 256) wv[i] = Wv[i];
    }
    __syncthreads();

    const int tx = threadIdx.x & 31;   // col group: cols c0..c0+3
    const int ty = threadIdx.x >> 5;   // 0..7 row phase
    const int c0 = tx * 4;
    const int r0 = blockIdx.x * 64;

    float acc[8][4];
#pragma unroll
    for (int rr = 0; rr < 8; ++rr)
#pragma unroll
        for (int j = 0; j < 4; ++j) acc[rr][j] = 0.0f;

    int rows[8];
#pragma unroll
    for (int rr = 0; rr < 8; ++rr) {
        int r = r0 + ty + 8 * rr;
        rows[rr] = (r < N) ? r : (N - 1);
    }

    for (int k4 = 0; k4 < 32; ++k4) {
        const int kb = k4 * 4;
        const float4 w0 = *reinterpret_cast<const float4*>(&wl[(kb + 0) * 128 + c0]);
        const float4 w1 = *reinterpret_cast<const float4*>(&wl[(kb + 1) * 128 + c0]);
        const float4 w2 = *reinterpret_cast<const float4*>(&wl[(kb + 2) * 128 + c0]);
        const float4 w3 = *reinterpret_cast<const float4*>(&wl[(kb + 3) * 128 + c0]);
#pragma unroll
        for (int rr = 0; rr < 8; ++rr) {
            const float4 a = *reinterpret_cast<const float4*>(A + (size_t)rows[rr] * H128 + kb);
            acc[rr][0] = fmaf(a.w, w3.x, fmaf(a.z, w2.x, fmaf(a.y, w1.x, fmaf(a.x, w0.x, acc[rr][0]))));
            acc[rr][1] = fmaf(a.w, w3.y, fmaf(a.z, w2.y, fmaf(a.y, w1.y, fmaf(a.x, w0.y, acc[rr][1]))));
            acc[rr][2] = fmaf(a.w, w3.z, fmaf(a.z, w2.z, fmaf(a.y, w1.z, fmaf(a.x, w0.z, acc[rr][2]))));
            acc[rr][3] = fmaf(a.w, w3.w, fmaf(a.z, w2.w, fmaf(a.y, w1.w, fmaf(a.x, w0.w, acc[rr][3]))));
        }
    }

    const float b0 = bias[c0 + 0], b1v = bias[c0 + 1], b2v = bias[c0 + 2], b3v = bias[c0 + 3];
#pragma unroll
    for (int rr = 0; rr < 8; ++rr) {
        int r = r0 + ty + 8 * rr;
        if (r >= N) continue;
        float o[4];
        o[0] = acc[rr][0] + b0;
        o[1] = acc[rr][1] + b1v;
        o[2] = acc[rr][2] + b2v;
        o[3] = acc[rr][3] + b3v;
        if (dogelu) {
#pragma unroll
            for (int j = 0; j < 4; ++j)
                o[j] = 0.5f * o[j] * (1.0f + erff(o[j] * 0.70710678118654752440f));
        }
        *reinterpret_cast<float4*>(out + (size_t)r * H128 + c0) =
            make_float4(o[0], o[1], o[2], o[3]);
    }
}

// ---------- K7: out[i] = reports[leader[i]] ----------
__global__ void k_gather(const int* __restrict__ leader, const float* __restrict__ reports,
                         float* __restrict__ out, int N) {
    long long g = (long long)blockIdx.x * blockDim.x + threadIdx.x;
    if (g >= (long long)N * 32) return;
    int i = (int)(g >> 5);
    int q = (int)(g & 31);
    int l = leader[i];
    if (l < 0) l = i;
    *reinterpret_cast<float4*>(out + (size_t)i * H128 + q * 4) =
        *reinterpret_cast<const float4*>(reports + (size_t)l * H128 + q * 4);
}

extern "C" void kernel_launch(void* const* d_in, const int* in_sizes, int n_in,
                              void* d_out, int out_size, void* d_ws, size_t ws_size,
                              hipStream_t stream) {
    const float* x     = (const float*)d_in[0];
    const int*   ei    = (const int*)d_in[1];
    const float* wlead = (const float*)d_in[2];
    const float* blead = (const float*)d_in[3];
    const float* w1    = (const float*)d_in[4];
    const float* b1    = (const float*)d_in[5];
    const float* w2    = (const float*)d_in[6];
    const float* b2    = (const float*)d_in[7];
    float* out = (float*)d_out;

    const int N = in_sizes[0] / H128;
    const int E = in_sizes[1] / 2;
    const int NCH = (N + CHUNK - 1) / CHUNK;

    char* ws = (char*)d_ws;
    size_t off = 0;
    float* sums = (float*)(ws + off); off += (size_t)N * H128 * 4;       // 51.2 MB (mean, then reports)
    double* logits = (double*)(ws + off); off += (size_t)N * 8;
    unsigned long long* segmax = (unsigned long long*)(ws + off); off += (size_t)N * 8;
    int* leader = (int*)(ws + off); off += (size_t)N * 4;
    int* deg    = (int*)(ws + off); off += (size_t)N * 4;
    int* starts = (int*)(ws + off); off += (size_t)(N + 1) * 4;
    int* cursor = (int*)(ws + off); off += (size_t)N * 4;
    int* csr    = (int*)(ws + off); off += (size_t)E * 4;                // 3.2 MB
    int* part   = (int*)(ws + off); off += (size_t)NCH * 4;
    float* hbuf = out;        // use d_out as the hidden buffer
    float* reports = sums;    // reuse mean buffer for reports

    hipMemsetAsync(segmax, 0, (size_t)N * 8, stream);
    hipMemsetAsync(leader, 0xFF, (size_t)N * 4, stream);
    hipMemsetAsync(deg, 0, (size_t)N * 4, stream);

    // leader election
    k_logits<<<(N + 3) / 4, 256, 0, stream>>>(x, wlead, blead, logits, N);
    const int M = E + N;
    k_segmax<<<(M + 255) / 256, 256, 0, stream>>>(ei, logits, segmax, E, N);
    k_leader<<<(M + 255) / 256, 256, 0, stream>>>(ei, logits, segmax, leader, E, N);

    // CSR by destination
    k_hist<<<(E + 255) / 256, 256, 0, stream>>>(ei, deg, E);
    k_scan_partial<<<NCH, 256, 0, stream>>>(deg, part, N);
    k_scan_offsets<<<1, 1, 0, stream>>>(part, NCH, starts, N);
    k_scan_write<<<NCH, 256, 0, stream>>>(deg, part, starts, cursor, N);
    k_fill<<<(E + 255) / 256, 256, 0, stream>>>(ei, cursor, csr, E);

    // gather-aggregate mean
    k_aggregate<<<(N + 7) / 8, 256, 0, stream>>>(starts, csr, x, sums, N);

    // MLP
    k_gemm128<<<(N + 63) / 64, 256, 0, stream>>>(sums, w1, b1, hbuf, N, 1);
    k_gemm128<<<(N + 63) / 64, 256, 0, stream>>>(hbuf, w2, b2, reports, N, 0);

    // leader-report broadcast
    const long long gc = (long long)N * 32;
    k_gather<<<(int)((gc + 255) / 256), 256, 0, stream>>>(leader, reports, out, N);
}

// Round 3
// 369.257 us; speedup vs baseline: 4.7282x; 1.4245x over previous
//
#include <hip/hip_runtime.h>
#include <math.h>

#define H128 128
#define CHUNK 1024

typedef short bf16x8 __attribute__((ext_vector_type(8)));
typedef float f32x4 __attribute__((ext_vector_type(4)));

// ---------- helpers ----------
__device__ __forceinline__ unsigned long long enc64(double d) {
    unsigned long long b = (unsigned long long)__double_as_longlong(d);
    return (b & 0x8000000000000000ULL) ? ~b : (b | 0x8000000000000000ULL);
}

__device__ __forceinline__ short f2bf(float f) {   // fp32 -> bf16 RNE
    unsigned u = __float_as_uint(f);
    unsigned r = (u + 0x7FFFu + ((u >> 16) & 1u)) >> 16;
    return (short)r;
}

// ---------- K1: logits[n] = dot(x[n], w_lead) + b_lead  (fp64) ----------
__global__ void k_logits(const float* __restrict__ x, const float* __restrict__ wl,
                         const float* __restrict__ bl, double* __restrict__ logits, int N) {
    int wave = (int)((blockIdx.x * (unsigned)blockDim.x + threadIdx.x) >> 6);
    int lane = threadIdx.x & 63;
    if (wave >= N) return;
    const float* xr = x + (size_t)wave * H128;
    double s = (double)xr[lane] * (double)wl[lane]
             + (double)xr[lane + 64] * (double)wl[lane + 64];
#pragma unroll
    for (int off = 32; off > 0; off >>= 1) s += __shfl_down(s, off);
    if (lane == 0) logits[wave] = s + (double)bl[0];
}

// ---------- CSR build: histogram ----------
__global__ void k_hist(const int* __restrict__ ei, int* __restrict__ deg, int E) {
    int t = blockIdx.x * blockDim.x + threadIdx.x;
    if (t >= E) return;
    atomicAdd(&deg[ei[E + t]], 1);
}

// ---------- CSR build: per-chunk partial sums ----------
__global__ void k_scan_partial(const int* __restrict__ deg, int* __restrict__ part, int N) {
    __shared__ int sm[256];
    int base = blockIdx.x * CHUNK;
    int s = 0;
    for (int i = threadIdx.x; i < CHUNK; i += 256) {
        int g = base + i;
        if (g < N) s += deg[g];
    }
    sm[threadIdx.x] = s;
    __syncthreads();
    for (int o = 128; o > 0; o >>= 1) {
        if (threadIdx.x < o) sm[threadIdx.x] += sm[threadIdx.x + o];
        __syncthreads();
    }
    if (threadIdx.x == 0) part[blockIdx.x] = sm[0];
}

// ---------- CSR build: scan the chunk partials, single thread ----------
__global__ void k_scan_offsets(int* __restrict__ part, int nch, int* __restrict__ starts, int N) {
    int acc = 0;
    for (int i = 0; i < nch; ++i) { int v = part[i]; part[i] = acc; acc += v; }
    starts[N] = acc;   // = E
}

// ---------- CSR build: write exclusive scan per chunk ----------
__global__ void k_scan_write(const int* __restrict__ deg, const int* __restrict__ part,
                             int* __restrict__ starts, int* __restrict__ cursor, int N) {
    __shared__ int sm[256];
    int base = blockIdx.x * CHUNK;
    int t = threadIdx.x;
    int i0 = base + t * 4;
    int v[4], ts = 0;
#pragma unroll
    for (int j = 0; j < 4; ++j) {
        int g = i0 + j;
        v[j] = (g < N) ? deg[g] : 0;
        ts += v[j];
    }
    sm[t] = ts;
    __syncthreads();
    for (int o = 1; o < 256; o <<= 1) {
        int add = (t >= o) ? sm[t - o] : 0;
        __syncthreads();
        sm[t] += add;
        __syncthreads();
    }
    int excl = sm[t] - ts + part[blockIdx.x];
#pragma unroll
    for (int j = 0; j < 4; ++j) {
        int g = i0 + j;
        if (g < N) { starts[g] = excl; cursor[g] = excl; excl += v[j]; }
    }
}

// ---------- CSR build: fill edge slots ----------
__global__ void k_fill(const int* __restrict__ ei, int* __restrict__ cursor,
                       int* __restrict__ csr, int E) {
    int t = blockIdx.x * blockDim.x + threadIdx.x;
    if (t >= E) return;
    int r = ei[t], c = ei[E + t];
    int pos = atomicAdd(&cursor[c], 1);
    csr[pos] = r;
}

// ---------- K4: gather-aggregate mean + fused leader election ----------
// 32 lanes per dst: float4/lane accumulation; lane 0 tracks lexicographic
// max of (enc64(logit[src]), src) over in-edges + self-loop — identical
// semantics to segment_max + argmax-by-max-src.
__global__ __launch_bounds__(256) void k_aggregate(const int* __restrict__ starts,
                                                   const int* __restrict__ csr,
                                                   const float* __restrict__ x,
                                                   const double* __restrict__ logits,
                                                   float* __restrict__ mean,
                                                   int* __restrict__ leader, int N) {
    int d = blockIdx.x * 8 + (threadIdx.x >> 5);
    int lane = threadIdx.x & 31;
    if (d >= N) return;
    int s = starts[d], e = starts[d + 1];
    float4 acc = make_float4(0.f, 0.f, 0.f, 0.f);
    unsigned long long best = 0; int bsrc = 0;
    if (lane == 0) { best = enc64(logits[d]); bsrc = d; }   // self-loop seed
    for (int j = s; j < e; ++j) {
        int r = csr[j];
        const float4 v = *reinterpret_cast<const float4*>(x + (size_t)r * H128 + lane * 4);
        acc.x += v.x; acc.y += v.y; acc.z += v.z; acc.w += v.w;
        if (lane == 0) {
            unsigned long long lg = enc64(logits[r]);
            if (lg > best || (lg == best && r > bsrc)) { best = lg; bsrc = r; }
        }
    }
    if (lane == 0) leader[d] = bsrc;
    float inv = 1.0f / fmaxf((float)(e - s), 1.0f);
    acc.x *= inv; acc.y *= inv; acc.z *= inv; acc.w *= inv;
    *reinterpret_cast<float4*>(mean + (size_t)d * H128 + lane * 4) = acc;
}

// ---------- K5/K6: MFMA GEMM: out[n,:] = act(A[n,:] @ W + bias) ----------
// Operand swap: D = W^T (A_op) x A^T (B_op) so each lane's f32x4 holds 4
// consecutive output channels of one node -> coalesced float4 stores.
// W^T staged in LDS as bf16 [128][136] (272B row stride: b128-aligned, 2-way banks).
// Block 256 = 4 waves x 32 rows = 128 rows.
__global__ __launch_bounds__(256, 2) void k_gemm_mfma(
        const float* __restrict__ A, const float* __restrict__ W,
        const float* __restrict__ bias, float* __restrict__ out, int N, int dogelu) {
    __shared__ short wlT[128][136];
    // stage W^T (fp32 -> bf16)
    for (int i = threadIdx.x; i < 4096; i += 256) {
        int k = i >> 5;              // W row (k index)
        int n4 = (i & 31) * 4;       // 4 output channels
        float4 w = reinterpret_cast<const float4*>(W)[i];
        wlT[n4 + 0][k] = f2bf(w.x);
        wlT[n4 + 1][k] = f2bf(w.y);
        wlT[n4 + 2][k] = f2bf(w.z);
        wlT[n4 + 3][k] = f2bf(w.w);
    }
    __syncthreads();

    const int wid = threadIdx.x >> 6;
    const int lane = threadIdx.x & 63;
    const int row0 = blockIdx.x * 128 + wid * 32;
    const int kblk = (lane >> 4) * 8;          // k offset of this lane's 8 elems

    // load + convert the wave's A fragments (2 node-tiles x 4 k-steps)
    bf16x8 xf[2][4];
#pragma unroll
    for (int t = 0; t < 2; ++t) {
        int r = row0 + t * 16 + (lane & 15);
        if (r >= N) r = N - 1;
        const float* ap = A + (size_t)r * H128 + kblk;
#pragma unroll
        for (int s = 0; s < 4; ++s) {
            float4 a0 = *reinterpret_cast<const float4*>(ap + s * 32);
            float4 a1 = *reinterpret_cast<const float4*>(ap + s * 32 + 4);
            bf16x8 v;
            v[0] = f2bf(a0.x); v[1] = f2bf(a0.y); v[2] = f2bf(a0.z); v[3] = f2bf(a0.w);
            v[4] = f2bf(a1.x); v[5] = f2bf(a1.y); v[6] = f2bf(a1.z); v[7] = f2bf(a1.w);
            xf[t][s] = v;
        }
    }

    f32x4 acc[2][8];
#pragma unroll
    for (int t = 0; t < 2; ++t)
#pragma unroll
        for (int cb = 0; cb < 8; ++cb)
#pragma unroll
            for (int j = 0; j < 4; ++j) acc[t][cb][j] = 0.0f;

#pragma unroll
    for (int cb = 0; cb < 8; ++cb) {
        const int ch = cb * 16 + (lane & 15);
#pragma unroll
        for (int s = 0; s < 4; ++s) {
            bf16x8 wf = *reinterpret_cast<bf16x8*>(&wlT[ch][s * 32 + kblk]);
            acc[0][cb] = __builtin_amdgcn_mfma_f32_16x16x32_bf16(wf, xf[0][s], acc[0][cb], 0, 0, 0);
            acc[1][cb] = __builtin_amdgcn_mfma_f32_16x16x32_bf16(wf, xf[1][s], acc[1][cb], 0, 0, 0);
        }
    }

    const int chq = (lane >> 4) * 4;           // first of 4 channels this lane holds
#pragma unroll
    for (int cb = 0; cb < 8; ++cb) {
        const float4 bv = *reinterpret_cast<const float4*>(&bias[cb * 16 + chq]);
#pragma unroll
        for (int t = 0; t < 2; ++t) {
            int node = row0 + t * 16 + (lane & 15);
            if (node >= N) continue;
            float o[4];
            o[0] = acc[t][cb][0] + bv.x;
            o[1] = acc[t][cb][1] + bv.y;
            o[2] = acc[t][cb][2] + bv.z;
            o[3] = acc[t][cb][3] + bv.w;
            if (dogelu) {
#pragma unroll
                for (int j = 0; j < 4; ++j)
                    o[j] = 0.5f * o[j] * (1.0f + erff(o[j] * 0.70710678118654752440f));
            }
            *reinterpret_cast<float4*>(out + (size_t)node * H128 + cb * 16 + chq) =
                make_float4(o[0], o[1], o[2], o[3]);
        }
    }
}

// ---------- K7: out[i] = reports[leader[i]] ----------
__global__ void k_gather(const int* __restrict__ leader, const float* __restrict__ reports,
                         float* __restrict__ out, int N) {
    long long g = (long long)blockIdx.x * blockDim.x + threadIdx.x;
    if (g >= (long long)N * 32) return;
    int i = (int)(g >> 5);
    int q = (int)(g & 31);
    int l = leader[i];
    *reinterpret_cast<float4*>(out + (size_t)i * H128 + q * 4) =
        *reinterpret_cast<const float4*>(reports + (size_t)l * H128 + q * 4);
}

extern "C" void kernel_launch(void* const* d_in, const int* in_sizes, int n_in,
                              void* d_out, int out_size, void* d_ws, size_t ws_size,
                              hipStream_t stream) {
    const float* x     = (const float*)d_in[0];
    const int*   ei    = (const int*)d_in[1];
    const float* wlead = (const float*)d_in[2];
    const float* blead = (const float*)d_in[3];
    const float* w1    = (const float*)d_in[4];
    const float* b1    = (const float*)d_in[5];
    const float* w2    = (const float*)d_in[6];
    const float* b2    = (const float*)d_in[7];
    float* out = (float*)d_out;

    const int N = in_sizes[0] / H128;
    const int E = in_sizes[1] / 2;
    const int NCH = (N + CHUNK - 1) / CHUNK;

    char* ws = (char*)d_ws;
    size_t off = 0;
    float* sums = (float*)(ws + off); off += (size_t)N * H128 * 4;   // mean, then reports
    double* logits = (double*)(ws + off); off += (size_t)N * 8;
    int* leader = (int*)(ws + off); off += (size_t)N * 4;
    int* deg    = (int*)(ws + off); off += (size_t)N * 4;
    int* starts = (int*)(ws + off); off += (size_t)(N + 1) * 4;
    int* cursor = (int*)(ws + off); off += (size_t)N * 4;
    int* csr    = (int*)(ws + off); off += (size_t)E * 4;
    int* part   = (int*)(ws + off); off += (size_t)NCH * 4;
    float* hbuf = out;        // d_out doubles as the hidden buffer
    float* reports = sums;    // mean buffer reused for reports

    hipMemsetAsync(deg, 0, (size_t)N * 4, stream);

    // leader logits
    k_logits<<<(N + 3) / 4, 256, 0, stream>>>(x, wlead, blead, logits, N);

    // CSR by destination
    k_hist<<<(E + 255) / 256, 256, 0, stream>>>(ei, deg, E);
    k_scan_partial<<<NCH, 256, 0, stream>>>(deg, part, N);
    k_scan_offsets<<<1, 1, 0, stream>>>(part, NCH, starts, N);
    k_scan_write<<<NCH, 256, 0, stream>>>(deg, part, starts, cursor, N);
    k_fill<<<(E + 255) / 256, 256, 0, stream>>>(ei, cursor, csr, E);

    // gather-aggregate mean + leader election
    k_aggregate<<<(N + 7) / 8, 256, 0, stream>>>(starts, csr, x, logits, sums, leader, N);

    // MLP (bf16 MFMA)
    k_gemm_mfma<<<(N + 127) / 128, 256, 0, stream>>>(sums, w1, b1, hbuf, N, 1);
    k_gemm_mfma<<<(N + 127) / 128, 256, 0, stream>>>(hbuf, w2, b2, reports, N, 0);

    // leader-report broadcast
    const long long gc = (long long)N * 32;
    k_gather<<<(int)((gc + 255) / 256), 256, 0, stream>>>(leader, reports, out, N);
}

// Round 4
// 328.191 us; speedup vs baseline: 5.3198x; 1.1251x over previous
//
#include <hip/hip_runtime.h>
#include <math.h>

#define H128 128
#define CHUNK 1024

typedef short bf16x8 __attribute__((ext_vector_type(8)));
typedef float f32x4 __attribute__((ext_vector_type(4)));

// ---------- helpers ----------
__device__ __forceinline__ unsigned long long enc64(double d) {
    unsigned long long b = (unsigned long long)__double_as_longlong(d);
    return (b & 0x8000000000000000ULL) ? ~b : (b | 0x8000000000000000ULL);
}

__device__ __forceinline__ unsigned short f2bf(float f) {   // fp32 -> bf16 RNE
    unsigned u = __float_as_uint(f);
    return (unsigned short)((u + 0x7FFFu + ((u >> 16) & 1u)) >> 16);
}

__device__ __forceinline__ float bf2f(unsigned short b) {
    return __uint_as_float((unsigned)b << 16);
}

// ---------- K1: fused logits (fp64) + x -> bf16 conversion ----------
__global__ void k_prep(const float* __restrict__ x, const float* __restrict__ wl,
                       const float* __restrict__ bl, unsigned short* __restrict__ xb,
                       double* __restrict__ logits, int N) {
    int wave = (int)((blockIdx.x * (unsigned)blockDim.x + threadIdx.x) >> 6);
    int lane = threadIdx.x & 63;
    if (wave >= N) return;
    const float2 v = *reinterpret_cast<const float2*>(x + (size_t)wave * H128 + lane * 2);
    const float2 w = *reinterpret_cast<const float2*>(wl + lane * 2);
    unsigned p = (unsigned)f2bf(v.x) | ((unsigned)f2bf(v.y) << 16);
    *reinterpret_cast<unsigned*>(xb + (size_t)wave * H128 + lane * 2) = p;
    double s = (double)v.x * (double)w.x + (double)v.y * (double)w.y;
#pragma unroll
    for (int off = 32; off > 0; off >>= 1) s += __shfl_down(s, off);
    if (lane == 0) logits[wave] = s + (double)bl[0];
}

// ---------- CSR build: histogram ----------
__global__ void k_hist(const int* __restrict__ ei, int* __restrict__ deg, int E) {
    int t = blockIdx.x * blockDim.x + threadIdx.x;
    if (t >= E) return;
    atomicAdd(&deg[ei[E + t]], 1);
}

// ---------- CSR build: per-chunk partial sums ----------
__global__ void k_scan_partial(const int* __restrict__ deg, int* __restrict__ part, int N) {
    __shared__ int sm[256];
    int base = blockIdx.x * CHUNK;
    int s = 0;
    for (int i = threadIdx.x; i < CHUNK; i += 256) {
        int g = base + i;
        if (g < N) s += deg[g];
    }
    sm[threadIdx.x] = s;
    __syncthreads();
    for (int o = 128; o > 0; o >>= 1) {
        if (threadIdx.x < o) sm[threadIdx.x] += sm[threadIdx.x + o];
        __syncthreads();
    }
    if (threadIdx.x == 0) part[blockIdx.x] = sm[0];
}

// ---------- CSR build: scan the chunk partials, single thread ----------
__global__ void k_scan_offsets(int* __restrict__ part, int nch, int* __restrict__ starts, int N) {
    int acc = 0;
    for (int i = 0; i < nch; ++i) { int v = part[i]; part[i] = acc; acc += v; }
    starts[N] = acc;   // = E
}

// ---------- CSR build: write exclusive scan per chunk ----------
__global__ void k_scan_write(const int* __restrict__ deg, const int* __restrict__ part,
                             int* __restrict__ starts, int* __restrict__ cursor, int N) {
    __shared__ int sm[256];
    int base = blockIdx.x * CHUNK;
    int t = threadIdx.x;
    int i0 = base + t * 4;
    int v[4], ts = 0;
#pragma unroll
    for (int j = 0; j < 4; ++j) {
        int g = i0 + j;
        v[j] = (g < N) ? deg[g] : 0;
        ts += v[j];
    }
    sm[t] = ts;
    __syncthreads();
    for (int o = 1; o < 256; o <<= 1) {
        int add = (t >= o) ? sm[t - o] : 0;
        __syncthreads();
        sm[t] += add;
        __syncthreads();
    }
    int excl = sm[t] - ts + part[blockIdx.x];
#pragma unroll
    for (int j = 0; j < 4; ++j) {
        int g = i0 + j;
        if (g < N) { starts[g] = excl; cursor[g] = excl; excl += v[j]; }
    }
}

// ---------- CSR build: fill edge slots ----------
__global__ void k_fill(const int* __restrict__ ei, int* __restrict__ cursor,
                       int* __restrict__ csr, int E) {
    int t = blockIdx.x * blockDim.x + threadIdx.x;
    if (t >= E) return;
    int r = ei[t], c = ei[E + t];
    int pos = atomicAdd(&cursor[c], 1);
    csr[pos] = r;
}

// ---------- K4: bf16 gather-aggregate mean + fused leader election ----------
// 32 lanes per dst, ushort4 (4 bf16 = 8B) per lane, fp32 accumulate,
// bf16 mean output. Lane 0 tracks lexicographic max (enc64(logit), src).
__global__ __launch_bounds__(256) void k_aggregate(const int* __restrict__ starts,
                                                   const int* __restrict__ csr,
                                                   const unsigned short* __restrict__ xb,
                                                   const double* __restrict__ logits,
                                                   unsigned short* __restrict__ meanb,
                                                   int* __restrict__ leader, int N) {
    int d = blockIdx.x * 8 + (threadIdx.x >> 5);
    int lane = threadIdx.x & 31;
    if (d >= N) return;
    int s = starts[d], e = starts[d + 1];
    float a0 = 0.f, a1 = 0.f, a2 = 0.f, a3 = 0.f;
    unsigned long long best = 0; int bsrc = 0;
    if (lane == 0) { best = enc64(logits[d]); bsrc = d; }   // self-loop seed
    int j = s;
    for (; j + 2 <= e; j += 2) {
        int r0 = csr[j], r1 = csr[j + 1];
        const ushort4 v0 = *reinterpret_cast<const ushort4*>(xb + (size_t)r0 * H128 + lane * 4);
        const ushort4 v1 = *reinterpret_cast<const ushort4*>(xb + (size_t)r1 * H128 + lane * 4);
        a0 += bf2f(v0.x) + bf2f(v1.x);
        a1 += bf2f(v0.y) + bf2f(v1.y);
        a2 += bf2f(v0.z) + bf2f(v1.z);
        a3 += bf2f(v0.w) + bf2f(v1.w);
        if (lane == 0) {
            unsigned long long lg = enc64(logits[r0]);
            if (lg > best || (lg == best && r0 > bsrc)) { best = lg; bsrc = r0; }
            lg = enc64(logits[r1]);
            if (lg > best || (lg == best && r1 > bsrc)) { best = lg; bsrc = r1; }
        }
    }
    if (j < e) {
        int r0 = csr[j];
        const ushort4 v0 = *reinterpret_cast<const ushort4*>(xb + (size_t)r0 * H128 + lane * 4);
        a0 += bf2f(v0.x); a1 += bf2f(v0.y); a2 += bf2f(v0.z); a3 += bf2f(v0.w);
        if (lane == 0) {
            unsigned long long lg = enc64(logits[r0]);
            if (lg > best || (lg == best && r0 > bsrc)) { best = lg; bsrc = r0; }
        }
    }
    if (lane == 0) leader[d] = bsrc;
    float inv = 1.0f / fmaxf((float)(e - s), 1.0f);
    ushort4 mo;
    mo.x = f2bf(a0 * inv); mo.y = f2bf(a1 * inv);
    mo.z = f2bf(a2 * inv); mo.w = f2bf(a3 * inv);
    *reinterpret_cast<ushort4*>(meanb + (size_t)d * H128 + lane * 4) = mo;
}

// ---------- K5/K6: MFMA GEMM: out[n,:] = act(A[rowsel(n),:] @ W + bias) ----------
// Operand swap: D = W^T (A_op) x A^T (B_op); lane's f32x4 = 4 consecutive
// output channels of one node -> coalesced stores. A is bf16, loaded as
// bf16x8 fragments directly. Optional row gather through `leader`
// (fused reports[leader] for the second GEMM). Output fp32 or bf16.
__global__ __launch_bounds__(256, 2) void k_gemm_mfma(
        const unsigned short* __restrict__ A, const float* __restrict__ W,
        const float* __restrict__ bias, const int* __restrict__ leader,
        float* __restrict__ outf, unsigned short* __restrict__ outb,
        int N, int dogelu) {
    __shared__ unsigned short wlT[128][136];
    // stage W^T (fp32 -> bf16)
    for (int i = threadIdx.x; i < 4096; i += 256) {
        int k = i >> 5;              // W row (k index)
        int n4 = (i & 31) * 4;       // 4 output channels
        float4 w = reinterpret_cast<const float4*>(W)[i];
        wlT[n4 + 0][k] = f2bf(w.x);
        wlT[n4 + 1][k] = f2bf(w.y);
        wlT[n4 + 2][k] = f2bf(w.z);
        wlT[n4 + 3][k] = f2bf(w.w);
    }
    __syncthreads();

    const int wid = threadIdx.x >> 6;
    const int lane = threadIdx.x & 63;
    const int row0 = blockIdx.x * 128 + wid * 32;
    const int kblk = (lane >> 4) * 8;

    int rows[2];
#pragma unroll
    for (int t = 0; t < 2; ++t) {
        int node = row0 + t * 16 + (lane & 15);
        int r = (node < N) ? node : (N - 1);
        if (leader) r = leader[r];
        rows[t] = r;
    }

    bf16x8 xf[2][4];
#pragma unroll
    for (int t = 0; t < 2; ++t)
#pragma unroll
        for (int s = 0; s < 4; ++s)
            xf[t][s] = *reinterpret_cast<const bf16x8*>(A + (size_t)rows[t] * H128 + s * 32 + kblk);

    f32x4 acc[2][8];
#pragma unroll
    for (int t = 0; t < 2; ++t)
#pragma unroll
        for (int cb = 0; cb < 8; ++cb)
#pragma unroll
            for (int j = 0; j < 4; ++j) acc[t][cb][j] = 0.0f;

#pragma unroll
    for (int cb = 0; cb < 8; ++cb) {
        const int ch = cb * 16 + (lane & 15);
#pragma unroll
        for (int s = 0; s < 4; ++s) {
            bf16x8 wf = *reinterpret_cast<bf16x8*>(&wlT[ch][s * 32 + kblk]);
            acc[0][cb] = __builtin_amdgcn_mfma_f32_16x16x32_bf16(wf, xf[0][s], acc[0][cb], 0, 0, 0);
            acc[1][cb] = __builtin_amdgcn_mfma_f32_16x16x32_bf16(wf, xf[1][s], acc[1][cb], 0, 0, 0);
        }
    }

    const int chq = (lane >> 4) * 4;
#pragma unroll
    for (int cb = 0; cb < 8; ++cb) {
        const float4 bv = *reinterpret_cast<const float4*>(&bias[cb * 16 + chq]);
#pragma unroll
        for (int t = 0; t < 2; ++t) {
            int node = row0 + t * 16 + (lane & 15);
            if (node >= N) continue;
            float o[4];
            o[0] = acc[t][cb][0] + bv.x;
            o[1] = acc[t][cb][1] + bv.y;
            o[2] = acc[t][cb][2] + bv.z;
            o[3] = acc[t][cb][3] + bv.w;
            if (dogelu) {
#pragma unroll
                for (int j = 0; j < 4; ++j)
                    o[j] = 0.5f * o[j] * (1.0f + erff(o[j] * 0.70710678118654752440f));
            }
            if (outb) {
                ushort4 ov;
                ov.x = f2bf(o[0]); ov.y = f2bf(o[1]); ov.z = f2bf(o[2]); ov.w = f2bf(o[3]);
                *reinterpret_cast<ushort4*>(outb + (size_t)node * H128 + cb * 16 + chq) = ov;
            } else {
                *reinterpret_cast<float4*>(outf + (size_t)node * H128 + cb * 16 + chq) =
                    make_float4(o[0], o[1], o[2], o[3]);
            }
        }
    }
}

extern "C" void kernel_launch(void* const* d_in, const int* in_sizes, int n_in,
                              void* d_out, int out_size, void* d_ws, size_t ws_size,
                              hipStream_t stream) {
    const float* x     = (const float*)d_in[0];
    const int*   ei    = (const int*)d_in[1];
    const float* wlead = (const float*)d_in[2];
    const float* blead = (const float*)d_in[3];
    const float* w1    = (const float*)d_in[4];
    const float* b1    = (const float*)d_in[5];
    const float* w2    = (const float*)d_in[6];
    const float* b2    = (const float*)d_in[7];
    float* out = (float*)d_out;

    const int N = in_sizes[0] / H128;
    const int E = in_sizes[1] / 2;
    const int NCH = (N + CHUNK - 1) / CHUNK;

    char* ws = (char*)d_ws;
    size_t off = 0;
    unsigned short* xb    = (unsigned short*)(ws + off); off += (size_t)N * H128 * 2;  // 25.6 MB
    unsigned short* meanb = (unsigned short*)(ws + off); off += (size_t)N * H128 * 2;  // 25.6 MB
    unsigned short* hbuf  = (unsigned short*)(ws + off); off += (size_t)N * H128 * 2;  // 25.6 MB
    double* logits = (double*)(ws + off); off += (size_t)N * 8;
    int* leader = (int*)(ws + off); off += (size_t)N * 4;
    int* deg    = (int*)(ws + off); off += (size_t)N * 4;
    int* starts = (int*)(ws + off); off += (size_t)(N + 1) * 4;
    int* cursor = (int*)(ws + off); off += (size_t)N * 4;
    int* csr    = (int*)(ws + off); off += (size_t)E * 4;
    int* part   = (int*)(ws + off); off += (size_t)NCH * 4;

    hipMemsetAsync(deg, 0, (size_t)N * 4, stream);

    // fused logits + bf16 conversion
    k_prep<<<(N + 3) / 4, 256, 0, stream>>>(x, wlead, blead, xb, logits, N);

    // CSR by destination
    k_hist<<<(E + 255) / 256, 256, 0, stream>>>(ei, deg, E);
    k_scan_partial<<<NCH, 256, 0, stream>>>(deg, part, N);
    k_scan_offsets<<<1, 1, 0, stream>>>(part, NCH, starts, N);
    k_scan_write<<<NCH, 256, 0, stream>>>(deg, part, starts, cursor, N);
    k_fill<<<(E + 255) / 256, 256, 0, stream>>>(ei, cursor, csr, E);

    // gather-aggregate mean (bf16) + leader election
    k_aggregate<<<(N + 7) / 8, 256, 0, stream>>>(starts, csr, xb, logits, meanb, leader, N);

    // MLP: GEMM1 (mean -> h, gelu, bf16), GEMM2 fused with leader-gather (-> out fp32)
    k_gemm_mfma<<<(N + 127) / 128, 256, 0, stream>>>(meanb, w1, b1, nullptr, nullptr, hbuf, N, 1);
    k_gemm_mfma<<<(N + 127) / 128, 256, 0, stream>>>(hbuf, w2, b2, leader, out, nullptr, N, 0);
}

// Round 5
// 262.140 us; speedup vs baseline: 6.6602x; 1.2520x over previous
//
#include <hip/hip_runtime.h>
#include <math.h>

#define H128 128
#define NBLK 64      // blocks for the binning passes
#define BKT 256      // dsts per bucket
#define MAXNB 512    // max buckets supported (N <= 131072)

typedef short bf16x8 __attribute__((ext_vector_type(8)));
typedef unsigned short u16x8 __attribute__((ext_vector_type(8)));
typedef float f32x4 __attribute__((ext_vector_type(4)));

// ---------- helpers ----------
__device__ __forceinline__ unsigned long long enc64(double d) {
    unsigned long long b = (unsigned long long)__double_as_longlong(d);
    return (b & 0x8000000000000000ULL) ? ~b : (b | 0x8000000000000000ULL);
}

__device__ __forceinline__ unsigned short f2bf(float f) {   // fp32 -> bf16 RNE
    unsigned u = __float_as_uint(f);
    return (unsigned short)((u + 0x7FFFu + ((u >> 16) & 1u)) >> 16);
}

__device__ __forceinline__ float bf2f(unsigned short b) {
    return __uint_as_float((unsigned)b << 16);
}

// ---------- K1: fused logits (fp64) + x -> bf16 conversion ----------
__global__ void k_prep(const float* __restrict__ x, const float* __restrict__ wl,
                       const float* __restrict__ bl, unsigned short* __restrict__ xb,
                       double* __restrict__ logits, int N) {
    int wave = (int)((blockIdx.x * (unsigned)blockDim.x + threadIdx.x) >> 6);
    int lane = threadIdx.x & 63;
    if (wave >= N) return;
    const float2 v = *reinterpret_cast<const float2*>(x + (size_t)wave * H128 + lane * 2);
    const float2 w = *reinterpret_cast<const float2*>(wl + lane * 2);
    unsigned p = (unsigned)f2bf(v.x) | ((unsigned)f2bf(v.y) << 16);
    *reinterpret_cast<unsigned*>(xb + (size_t)wave * H128 + lane * 2) = p;
    double s = (double)v.x * (double)w.x + (double)v.y * (double)w.y;
#pragma unroll
    for (int off = 32; off > 0; off >>= 1) s += __shfl_down(s, off);
    if (lane == 0) logits[wave] = s + (double)bl[0];
}

// ---------- binning pass 1: per-block LDS histogram over buckets ----------
__global__ __launch_bounds__(256) void k_bhist(const int* __restrict__ dsts,
        int* __restrict__ histg, int E, int NB) {
    __shared__ int h[MAXNB];
    for (int i = threadIdx.x; i < NB; i += 256) h[i] = 0;
    __syncthreads();
    int per = (E + NBLK - 1) / NBLK;
    int s = blockIdx.x * per;
    int e = min(E, s + per);
    for (int j = s + threadIdx.x; j < e; j += 256)
        atomicAdd(&h[dsts[j] >> 8], 1);
    __syncthreads();
    for (int i = threadIdx.x; i < NB; i += 256)
        histg[i * NBLK + blockIdx.x] = h[i];   // bucket-major
}

// ---------- binning pass 2: bucket totals + exclusive scan (single block) ----------
__global__ __launch_bounds__(MAXNB) void k_bscan(const int* __restrict__ histg,
        int* __restrict__ bstart, int NB) {
    __shared__ int sm[MAXNB];
    int t = threadIdx.x;
    int s = 0;
    if (t < NB) {
        const int4* p = reinterpret_cast<const int4*>(histg + t * NBLK);
#pragma unroll
        for (int i = 0; i < NBLK / 4; ++i) { int4 v = p[i]; s += v.x + v.y + v.z + v.w; }
    }
    sm[t] = s;
    __syncthreads();
    for (int o = 1; o < MAXNB; o <<= 1) {
        int add = (t >= o) ? sm[t - o] : 0;
        __syncthreads();
        sm[t] += add;
        __syncthreads();
    }
    if (t == 0) bstart[0] = 0;
    if (t < NB) bstart[t + 1] = sm[t];
}

// ---------- binning pass 3: per-(bucket,block) write cursors ----------
__global__ void k_base(const int* __restrict__ histg, const int* __restrict__ bstart,
                       int* __restrict__ base, int NB) {
    int b = blockIdx.x * blockDim.x + threadIdx.x;
    if (b >= NB) return;
    const int4* hp = reinterpret_cast<const int4*>(histg + b * NBLK);
    int acc = bstart[b];
    int4* bp = reinterpret_cast<int4*>(base + b * NBLK);
#pragma unroll
    for (int i = 0; i < NBLK / 4; ++i) {
        int4 h = hp[i];
        int4 o;
        o.x = acc; acc += h.x;
        o.y = acc; acc += h.y;
        o.z = acc; acc += h.z;
        o.w = acc; acc += h.w;
        bp[i] = o;
    }
}

// ---------- binning pass 4: scatter edges into bucket-segmented runs ----------
__global__ __launch_bounds__(256) void k_binscatter(const int* __restrict__ srcs,
        const int* __restrict__ dsts, const int* __restrict__ base,
        int2* __restrict__ binned, int E, int NB) {
    __shared__ int cur[MAXNB];
    for (int i = threadIdx.x; i < NB; i += 256)
        cur[i] = base[i * NBLK + blockIdx.x];
    __syncthreads();
    int per = (E + NBLK - 1) / NBLK;
    int s = blockIdx.x * per;
    int e = min(E, s + per);
    for (int j = s + threadIdx.x; j < e; j += 256) {
        int d = dsts[j], r = srcs[j];
        int pos = atomicAdd(&cur[d >> 8], 1);
        binned[pos] = make_int2(d, r);
    }
}

// ---------- binning pass 5: per-bucket local CSR (sequential global writes) ----------
__global__ __launch_bounds__(BKT) void k_localize(const int2* __restrict__ binned,
        const int* __restrict__ bstart, int* __restrict__ starts,
        int* __restrict__ csr, int N, int E, int NB) {
    __shared__ int deg[BKT];
    __shared__ int sm[BKT];
    __shared__ int cur[BKT];
    int b = blockIdx.x, t = threadIdx.x;
    int s0 = bstart[b], s1 = bstart[b + 1];
    deg[t] = 0;
    __syncthreads();
    for (int j = s0 + t; j < s1; j += BKT)
        atomicAdd(&deg[binned[j].x & (BKT - 1)], 1);
    __syncthreads();
    int v = deg[t];
    sm[t] = v;
    __syncthreads();
    for (int o = 1; o < BKT; o <<= 1) {
        int add = (t >= o) ? sm[t - o] : 0;
        __syncthreads();
        sm[t] += add;
        __syncthreads();
    }
    int excl = sm[t] - v;
    cur[t] = excl;
    int d = b * BKT + t;
    if (d < N) starts[d] = s0 + excl;
    if (b == NB - 1 && t == 0) starts[N] = E;
    __syncthreads();
    for (int j = s0 + t; j < s1; j += BKT) {
        int2 p = binned[j];
        int pos = atomicAdd(&cur[p.x & (BKT - 1)], 1);
        csr[s0 + pos] = p.y;
    }
}

// ---------- K4: bf16 gather-aggregate mean + lane-parallel leader election ----------
// 16 lanes per dst, ushort8 (16B) per lane, fp32 accumulate, bf16 mean out.
__global__ __launch_bounds__(256) void k_aggregate(const int* __restrict__ starts,
        const int* __restrict__ csr, const unsigned short* __restrict__ xb,
        const double* __restrict__ logits, unsigned short* __restrict__ meanb,
        int* __restrict__ leader, int N) {
    int d = blockIdx.x * 16 + (threadIdx.x >> 4);
    int lane = threadIdx.x & 15;
    if (d >= N) return;
    int s = starts[d], e = starts[d + 1];
    const unsigned short* xp = xb + lane * 8;
    float a[8];
#pragma unroll
    for (int i = 0; i < 8; ++i) a[i] = 0.f;
    int j = s;
    for (; j + 4 <= e; j += 4) {
        int r0 = csr[j], r1 = csr[j + 1], r2 = csr[j + 2], r3 = csr[j + 3];
        u16x8 v0 = *reinterpret_cast<const u16x8*>(xp + (size_t)r0 * H128);
        u16x8 v1 = *reinterpret_cast<const u16x8*>(xp + (size_t)r1 * H128);
        u16x8 v2 = *reinterpret_cast<const u16x8*>(xp + (size_t)r2 * H128);
        u16x8 v3 = *reinterpret_cast<const u16x8*>(xp + (size_t)r3 * H128);
#pragma unroll
        for (int i = 0; i < 8; ++i)
            a[i] += (bf2f(v0[i]) + bf2f(v1[i])) + (bf2f(v2[i]) + bf2f(v3[i]));
    }
    for (; j < e; ++j) {
        int r0 = csr[j];
        u16x8 v0 = *reinterpret_cast<const u16x8*>(xp + (size_t)r0 * H128);
#pragma unroll
        for (int i = 0; i < 8; ++i) a[i] += bf2f(v0[i]);
    }
    // leader election: lane-parallel lexicographic max of (enc64(logit), src)
    unsigned long long best; int bsrc;
    if (lane == 0) { best = enc64(logits[d]); bsrc = d; }   // self-loop seed
    else { best = 0ULL; bsrc = -1; }
    for (int k2 = s + lane; k2 < e; k2 += 16) {
        int r = csr[k2];
        unsigned long long lg = enc64(logits[r]);
        if (lg > best || (lg == best && r > bsrc)) { best = lg; bsrc = r; }
    }
#pragma unroll
    for (int o = 8; o > 0; o >>= 1) {
        unsigned long long ob = __shfl_xor(best, o);
        int os = __shfl_xor(bsrc, o);
        if (ob > best || (ob == best && os > bsrc)) { best = ob; bsrc = os; }
    }
    if (lane == 0) leader[d] = bsrc;
    float inv = 1.0f / fmaxf((float)(e - s), 1.0f);
    u16x8 mo;
#pragma unroll
    for (int i = 0; i < 8; ++i) mo[i] = f2bf(a[i] * inv);
    *reinterpret_cast<u16x8*>(meanb + (size_t)d * H128 + lane * 8) = mo;
}

// ---------- K5/K6: MFMA GEMM: out[n,:] = act(A[rowsel(n),:] @ W + bias) ----------
__global__ __launch_bounds__(256, 2) void k_gemm_mfma(
        const unsigned short* __restrict__ A, const float* __restrict__ W,
        const float* __restrict__ bias, const int* __restrict__ leader,
        float* __restrict__ outf, unsigned short* __restrict__ outb,
        int N, int dogelu) {
    __shared__ unsigned short wlT[128][136];
    for (int i = threadIdx.x; i < 4096; i += 256) {
        int k = i >> 5;              // W row (k index)
        int n4 = (i & 31) * 4;       // 4 output channels
        float4 w = reinterpret_cast<const float4*>(W)[i];
        wlT[n4 + 0][k] = f2bf(w.x);
        wlT[n4 + 1][k] = f2bf(w.y);
        wlT[n4 + 2][k] = f2bf(w.z);
        wlT[n4 + 3][k] = f2bf(w.w);
    }
    __syncthreads();

    const int wid = threadIdx.x >> 6;
    const int lane = threadIdx.x & 63;
    const int row0 = blockIdx.x * 128 + wid * 32;
    const int kblk = (lane >> 4) * 8;

    int rows[2];
#pragma unroll
    for (int t = 0; t < 2; ++t) {
        int node = row0 + t * 16 + (lane & 15);
        int r = (node < N) ? node : (N - 1);
        if (leader) r = leader[r];
        rows[t] = r;
    }

    bf16x8 xf[2][4];
#pragma unroll
    for (int t = 0; t < 2; ++t)
#pragma unroll
        for (int s = 0; s < 4; ++s)
            xf[t][s] = *reinterpret_cast<const bf16x8*>(A + (size_t)rows[t] * H128 + s * 32 + kblk);

    f32x4 acc[2][8];
#pragma unroll
    for (int t = 0; t < 2; ++t)
#pragma unroll
        for (int cb = 0; cb < 8; ++cb)
#pragma unroll
            for (int j = 0; j < 4; ++j) acc[t][cb][j] = 0.0f;

#pragma unroll
    for (int cb = 0; cb < 8; ++cb) {
        const int ch = cb * 16 + (lane & 15);
#pragma unroll
        for (int s = 0; s < 4; ++s) {
            bf16x8 wf = *reinterpret_cast<bf16x8*>(&wlT[ch][s * 32 + kblk]);
            acc[0][cb] = __builtin_amdgcn_mfma_f32_16x16x32_bf16(wf, xf[0][s], acc[0][cb], 0, 0, 0);
            acc[1][cb] = __builtin_amdgcn_mfma_f32_16x16x32_bf16(wf, xf[1][s], acc[1][cb], 0, 0, 0);
        }
    }

    const int chq = (lane >> 4) * 4;
#pragma unroll
    for (int cb = 0; cb < 8; ++cb) {
        const float4 bv = *reinterpret_cast<const float4*>(&bias[cb * 16 + chq]);
#pragma unroll
        for (int t = 0; t < 2; ++t) {
            int node = row0 + t * 16 + (lane & 15);
            if (node >= N) continue;
            float o[4];
            o[0] = acc[t][cb][0] + bv.x;
            o[1] = acc[t][cb][1] + bv.y;
            o[2] = acc[t][cb][2] + bv.z;
            o[3] = acc[t][cb][3] + bv.w;
            if (dogelu) {
#pragma unroll
                for (int j = 0; j < 4; ++j)
                    o[j] = 0.5f * o[j] * (1.0f + erff(o[j] * 0.70710678118654752440f));
            }
            if (outb) {
                ushort4 ov;
                ov.x = f2bf(o[0]); ov.y = f2bf(o[1]); ov.z = f2bf(o[2]); ov.w = f2bf(o[3]);
                *reinterpret_cast<ushort4*>(outb + (size_t)node * H128 + cb * 16 + chq) = ov;
            } else {
                *reinterpret_cast<float4*>(outf + (size_t)node * H128 + cb * 16 + chq) =
                    make_float4(o[0], o[1], o[2], o[3]);
            }
        }
    }
}

extern "C" void kernel_launch(void* const* d_in, const int* in_sizes, int n_in,
                              void* d_out, int out_size, void* d_ws, size_t ws_size,
                              hipStream_t stream) {
    const float* x     = (const float*)d_in[0];
    const int*   ei    = (const int*)d_in[1];
    const float* wlead = (const float*)d_in[2];
    const float* blead = (const float*)d_in[3];
    const float* w1    = (const float*)d_in[4];
    const float* b1    = (const float*)d_in[5];
    const float* w2    = (const float*)d_in[6];
    const float* b2    = (const float*)d_in[7];
    float* out = (float*)d_out;

    const int N = in_sizes[0] / H128;
    const int E = in_sizes[1] / 2;
    const int NB = (N + BKT - 1) / BKT;
    const int* srcs = ei;
    const int* dsts = ei + E;

    char* ws = (char*)d_ws;
    size_t off = 0;
    auto alloc = [&](size_t bytes) {
        void* p = ws + off;
        off = (off + bytes + 255) & ~(size_t)255;
        return p;
    };
    unsigned short* xb    = (unsigned short*)alloc((size_t)N * H128 * 2);
    unsigned short* meanb = (unsigned short*)alloc((size_t)N * H128 * 2);
    unsigned short* hbuf  = (unsigned short*)alloc((size_t)N * H128 * 2);
    double* logits = (double*)alloc((size_t)N * 8);
    int* leader = (int*)alloc((size_t)N * 4);
    int* starts = (int*)alloc((size_t)(N + 1) * 4);
    int* csr    = (int*)alloc((size_t)E * 4);
    int2* binned = (int2*)alloc((size_t)E * 8);
    int* histg  = (int*)alloc((size_t)NB * NBLK * 4);
    int* bstart = (int*)alloc((size_t)(NB + 1) * 4);
    int* base   = (int*)alloc((size_t)NB * NBLK * 4);

    // fused logits + bf16 conversion
    k_prep<<<(N + 3) / 4, 256, 0, stream>>>(x, wlead, blead, xb, logits, N);

    // atomic-free CSR build (LDS-binned)
    k_bhist<<<NBLK, 256, 0, stream>>>(dsts, histg, E, NB);
    k_bscan<<<1, MAXNB, 0, stream>>>(histg, bstart, NB);
    k_base<<<(NB + 255) / 256, 256, 0, stream>>>(histg, bstart, base, NB);
    k_binscatter<<<NBLK, 256, 0, stream>>>(srcs, dsts, base, binned, E, NB);
    k_localize<<<NB, BKT, 0, stream>>>(binned, bstart, starts, csr, N, E, NB);

    // gather-aggregate mean (bf16) + leader election
    k_aggregate<<<(N + 15) / 16, 256, 0, stream>>>(starts, csr, xb, logits, meanb, leader, N);

    // MLP: GEMM1 (mean -> h, gelu, bf16), GEMM2 fused with leader-gather (-> out fp32)
    k_gemm_mfma<<<(N + 127) / 128, 256, 0, stream>>>(meanb, w1, b1, nullptr, nullptr, hbuf, N, 1);
    k_gemm_mfma<<<(N + 127) / 128, 256, 0, stream>>>(hbuf, w2, b2, leader, out, nullptr, N, 0);
}